// Round 5
// baseline (688.631 us; speedup 1.0000x reference)
//
#include <hip/hip_runtime.h>
#include <cstddef>

// LIF constants (match numpy float64->float32 rounding)
static constexpr float A_MEM  = 0.951229424500714f;    // exp(-1/20)
static constexpr float A_SYN  = 0.8187307530779818f;   // exp(-1/5)
static constexpr float OM_MEM = 0.04877057549928599f;  // 1 - exp(-1/20)

// ---- fp32 GEMM, BN = full N (A fetched once), optional fused LayerNorm on A ----
// C[M,BN] = LN(A)[M,K] @ W[K,BN] + bias. 256 threads, microtile 8 x (CJ4*4).
// __launch_bounds__(256,1): allow full register allocation (round-4's 88-VGPR
// squeeze nullified the prefetch / spilled staging regs -> VALUBusy 44%).
template<int BM, int BN, int K, bool LN>
__global__ __launch_bounds__(256, 1) void gemm_ln(
    const float* __restrict__ A, const float* __restrict__ W,
    const float* __restrict__ bias,
    const float2* __restrict__ stats, const float* __restrict__ lnsc,
    const float* __restrict__ lnbi, float* __restrict__ C)
{
  constexpr int BK   = 16;
  constexpr int S    = K / BK;
  constexpr int PA   = BM + 4;          // pad: transposed-A writes 2-way max
  constexpr int NTYG = BM / 8;          // row groups (8 or 16)
  constexpr int NTX  = 256 / NTYG;      // threads across N (32 or 16)
  constexpr int CJ4  = BN / (NTX * 4);  // float4 col groups per thread
  constexpr int APT  = BM / 64;         // A float4 loads per thread
  constexpr int WPT  = BN / 64;         // W float4 loads per thread

  __shared__ float As[BK][PA];   // transposed: As[k][m]
  __shared__ float Ws[BK][BN];

  const int tid = threadIdx.x;
  const int tx  = tid % NTX;
  const int ty  = tid / NTX;
  const int m0  = blockIdx.x * BM;

  float4 aR[APT], wR[WPT];

  auto load_tile = [&](int k0) {
    #pragma unroll
    for (int p = 0; p < APT; ++p) {
      int idx = tid + p * 256;
      int r = idx >> 2, c4 = (idx & 3) << 2;
      float4 a = *(const float4*)(A + (size_t)(m0 + r) * K + k0 + c4);
      if constexpr (LN) {
        float2 st = stats[m0 + r];       // (mu, rsqrt(var+eps))
        float4 ls = *(const float4*)(lnsc + k0 + c4);
        float4 lb = *(const float4*)(lnbi + k0 + c4);
        a.x = (a.x - st.x) * st.y * ls.x + lb.x;
        a.y = (a.y - st.x) * st.y * ls.y + lb.y;
        a.z = (a.z - st.x) * st.y * ls.z + lb.z;
        a.w = (a.w - st.x) * st.y * ls.w + lb.w;
      }
      aR[p] = a;
    }
    #pragma unroll
    for (int p = 0; p < WPT; ++p) {
      int idx = tid + p * 256;
      int k = idx / (BN / 4), c4 = (idx % (BN / 4)) << 2;
      wR[p] = *(const float4*)(W + (size_t)(k0 + k) * BN + c4);
    }
  };

  auto store_tile = [&]() {
    #pragma unroll
    for (int p = 0; p < APT; ++p) {
      int idx = tid + p * 256;
      int r = idx >> 2, c4 = (idx & 3) << 2;
      As[c4 + 0][r] = aR[p].x;
      As[c4 + 1][r] = aR[p].y;
      As[c4 + 2][r] = aR[p].z;
      As[c4 + 3][r] = aR[p].w;
    }
    #pragma unroll
    for (int p = 0; p < WPT; ++p) {
      int idx = tid + p * 256;
      int k = idx / (BN / 4), c4 = (idx % (BN / 4)) << 2;
      *(float4*)&Ws[k][c4] = wR[p];
    }
  };

  float acc[8][CJ4 * 4];
  #pragma unroll
  for (int i = 0; i < 8; ++i)
    #pragma unroll
    for (int j = 0; j < CJ4 * 4; ++j) acc[i][j] = 0.f;

  load_tile(0);
  for (int s = 0; s < S; ++s) {
    __syncthreads();
    store_tile();
    __syncthreads();
    if (s + 1 < S) load_tile((s + 1) * BK);  // prefetch for next step
    // compiler fence: forbid sinking the prefetch loads into/past compute
    asm volatile("" ::: "memory");
    #pragma unroll
    for (int kk = 0; kk < BK; ++kk) {
      float4 a0 = *(const float4*)&As[kk][ty * 8];
      float4 a1 = *(const float4*)&As[kk][ty * 8 + 4];
      float av[8] = {a0.x, a0.y, a0.z, a0.w, a1.x, a1.y, a1.z, a1.w};
      float4 wv[CJ4];
      #pragma unroll
      for (int j = 0; j < CJ4; ++j)
        wv[j] = *(const float4*)&Ws[kk][tx * 4 + j * NTX * 4];
      #pragma unroll
      for (int i = 0; i < 8; ++i)
        #pragma unroll
        for (int j = 0; j < CJ4; ++j) {
          acc[i][4 * j + 0] += av[i] * wv[j].x;
          acc[i][4 * j + 1] += av[i] * wv[j].y;
          acc[i][4 * j + 2] += av[i] * wv[j].z;
          acc[i][4 * j + 3] += av[i] * wv[j].w;
        }
    }
  }

  #pragma unroll
  for (int j = 0; j < CJ4; ++j) {
    int col = tx * 4 + j * NTX * 4;
    float4 bb = *(const float4*)(bias + col);
    #pragma unroll
    for (int i = 0; i < 8; ++i) {
      int row = m0 + ty * 8 + i;
      float4 o;
      o.x = acc[i][4 * j + 0] + bb.x;
      o.y = acc[i][4 * j + 1] + bb.y;
      o.z = acc[i][4 * j + 2] + bb.z;
      o.w = acc[i][4 * j + 3] + bb.w;
      *(float4*)(C + (size_t)row * BN + col) = o;
    }
  }
}

// ---- LIF scan (in-place) + deterministic per-(b,t) LN stats (mu, rs) ----
template<int H, int BPB>   // BPB batches per 256-thread block
__global__ __launch_bounds__(256) void lif_stats(
    float* __restrict__ cur, float2* __restrict__ stats)
{
  constexpr int T = 128;
  constexpr int WPB = H / 64;   // waves per batch
  const int tid  = threadIdx.x;
  const int h    = tid % H;
  const size_t b = (size_t)blockIdx.x * BPB + tid / H;
  float* p = cur + b * T * H + h;
  __shared__ float w1[4][T], w2[4][T];
  const int wv = tid >> 6, lane = tid & 63;
  float v = 0.f, ci = 0.f;
  for (int t0 = 0; t0 < T; t0 += 4) {
    float ic[4];
    #pragma unroll
    for (int u = 0; u < 4; ++u) ic[u] = p[(size_t)(t0 + u) * H];  // 4 in flight
    #pragma unroll
    for (int u = 0; u < 4; ++u) {
      ci = A_SYN * ci + ic[u];
      v  = A_MEM * v + OM_MEM * ci;
      bool sp = v >= 1.0f;
      float xx = 4.0f * (v - 1.0f);
      float e  = __expf(xx);
      float tp = 1.0f + e;
      float sg = 4.0f * e / (tp * tp);   // == BETA/(2(1+cosh(BETA(v-1))))
      float o  = (sp ? 2.0f : 0.0f) - sg;
      v = sp ? 0.0f : v;
      ic[u] = o;
      float s1 = o, s2 = o * o;
      #pragma unroll
      for (int off = 1; off < 64; off <<= 1) {
        s1 += __shfl_xor(s1, off);
        s2 += __shfl_xor(s2, off);
      }
      if (lane == 0) { w1[wv][t0 + u] = s1; w2[wv][t0 + u] = s2; }
    }
    #pragma unroll
    for (int u = 0; u < 4; ++u) p[(size_t)(t0 + u) * H] = ic[u];
  }
  __syncthreads();
  if (tid < T * BPB) {
    int t  = tid & (T - 1);
    int bs = tid >> 7;
    float s1 = 0.f, s2 = 0.f;
    #pragma unroll
    for (int w = 0; w < WPB; ++w) {
      s1 += w1[bs * WPB + w][t];
      s2 += w2[bs * WPB + w][t];
    }
    float mu  = s1 * (1.0f / H);
    float var = s2 * (1.0f / H) - mu * mu;
    float rs  = rsqrtf(var + 1e-6f);
    stats[((size_t)blockIdx.x * BPB + bs) * T + t] = make_float2(mu, rs);
  }
}

// ---- layer-2 LIF scan + mean pool (no x3 materialization) ----
__global__ __launch_bounds__(256) void lif_pool(
    const float* __restrict__ cur, float* __restrict__ pooled)
{
  constexpr int T = 128, H = 64;
  int flat = blockIdx.x * 256 + threadIdx.x;   // b*64 + h
  int b = flat >> 6, h = flat & 63;
  const float* p = cur + (size_t)b * T * H + h;
  float v = 0.f, ci = 0.f, sum = 0.f;
  for (int t0 = 0; t0 < T; t0 += 4) {
    float ic[4];
    #pragma unroll
    for (int u = 0; u < 4; ++u) ic[u] = p[(size_t)(t0 + u) * H];
    #pragma unroll
    for (int u = 0; u < 4; ++u) {
      ci = A_SYN * ci + ic[u];
      v  = A_MEM * v + OM_MEM * ci;
      bool sp = v >= 1.0f;
      float xx = 4.0f * (v - 1.0f);
      float e  = __expf(xx);
      float tp = 1.0f + e;
      float sg = 4.0f * e / (tp * tp);
      sum += (sp ? 2.0f : 0.0f) - sg;
      v = sp ? 0.0f : v;
    }
  }
  pooled[flat] = sum * (1.0f / 128.0f);
}

// ---- head: logits = pooled @ Wc + bc ; mean = mean(pooled) ----
__global__ __launch_bounds__(1024) void head_k(
    const float* __restrict__ pooled, const float* __restrict__ Wc,
    const float* __restrict__ bc, float* __restrict__ logits,
    float* __restrict__ meanp)
{
  const int tid = threadIdx.x;
  const int b = tid >> 1, c = tid & 1;
  float accl = 0.f;
  #pragma unroll 8
  for (int k = 0; k < 64; ++k) accl += pooled[b * 64 + k] * Wc[k * 2 + c];
  logits[tid] = accl + bc[c];

  float s = 0.f;
  for (int i2 = tid; i2 < 512 * 64; i2 += 1024) s += pooled[i2];
  #pragma unroll
  for (int off = 32; off; off >>= 1) s += __shfl_xor(s, off);
  __shared__ float red[16];
  const int wave = tid >> 6, lane = tid & 63;
  if (lane == 0) red[wave] = s;
  __syncthreads();
  if (tid == 0) {
    float tot = 0.f;
    #pragma unroll
    for (int w = 0; w < 16; ++w) tot += red[w];
    meanp[0] = tot * (1.0f / 32768.0f);
  }
}

extern "C" void kernel_launch(void* const* d_in, const int* in_sizes, int n_in,
                              void* d_out, int out_size, void* d_ws, size_t ws_size,
                              hipStream_t stream) {
  const float* x    = (const float*)d_in[0];   // [512,128,512]
  const float* W0   = (const float*)d_in[1];   // [512,256]
  const float* b0   = (const float*)d_in[2];
  const float* ln1s = (const float*)d_in[3];
  const float* ln1b = (const float*)d_in[4];
  const float* W1   = (const float*)d_in[5];   // [256,128]
  const float* b1   = (const float*)d_in[6];
  const float* ln2s = (const float*)d_in[7];
  const float* ln2b = (const float*)d_in[8];
  const float* W2   = (const float*)d_in[9];   // [128,64]
  const float* b2   = (const float*)d_in[10];
  const float* Wc   = (const float*)d_in[11];  // [64,2]
  const float* bc   = (const float*)d_in[12];

  float* out    = (float*)d_out;
  float* logits = out;                 // [512,2]
  float* pooled = out + 1024;          // [512,64]
  float* meanp  = out + 1024 + 32768;  // [1]

  char* ws = (char*)d_ws;
  float*  cur0   = (float*)ws;                              // 64 MB [65536,256]
  float*  cur1   = (float*)(ws + (size_t)64 * 1024 * 1024); // 32 MB [65536,128]
  float*  cur2   = (float*)(ws + (size_t)96 * 1024 * 1024); // 16 MB [65536,64]
  float2* stats0 = (float2*)(ws + (size_t)112 * 1024 * 1024);           // 512 KB
  float2* stats1 = (float2*)(ws + (size_t)112 * 1024 * 1024 + 524288);  // 512 KB

  // layer 0: GEMM [65536,512]x[512,256]; scan + stats for LN1
  gemm_ln<64, 256, 512, false><<<1024, 256, 0, stream>>>(
      x, W0, b0, nullptr, nullptr, nullptr, cur0);
  lif_stats<256, 1><<<512, 256, 0, stream>>>(cur0, stats0);
  // layer 1: LN1 fused into staging; scan + stats for LN2
  gemm_ln<64, 128, 256, true><<<1024, 256, 0, stream>>>(
      cur0, W1, b1, stats0, ln1s, ln1b, cur1);
  lif_stats<128, 2><<<256, 256, 0, stream>>>(cur1, stats1);
  // layer 2: LN2 fused; scan + pool (x3 never materialized)
  gemm_ln<128, 64, 128, true><<<512, 256, 0, stream>>>(
      cur1, W2, b2, stats1, ln2s, ln2b, cur2);
  lif_pool<<<128, 256, 0, stream>>>(cur2, pooled);
  // head
  head_k<<<1, 1024, 0, stream>>>(pooled, Wc, bc, logits, meanp);
}

// Round 7
// 572.263 us; speedup vs baseline: 1.2033x; 1.2033x over previous
//
#include <hip/hip_runtime.h>
#include <cstddef>

// LIF constants (match numpy float64->float32 rounding)
static constexpr float A_MEM  = 0.951229424500714f;    // exp(-1/20)
static constexpr float A_SYN  = 0.8187307530779818f;   // exp(-1/5)
static constexpr float OM_MEM = 0.04877057549928599f;  // 1 - exp(-1/20)

__device__ inline float4 ln4(float4 a, float2 st, float4 ls, float4 lb) {
  a.x = (a.x - st.x) * st.y * ls.x + lb.x;
  a.y = (a.y - st.x) * st.y * ls.y + lb.y;
  a.z = (a.z - st.x) * st.y * ls.z + lb.z;
  a.w = (a.w - st.x) * st.y * ls.w + lb.w;
  return a;
}

// ---- fp32 GEMM, 128 x BN tile, 8 x NJ microtile, K-SEQUENTIAL accumulation ----
// (sequential K order matches np reference's fp32 summation -> zero spike flips)
template<int BN, int K, int N, bool LN>
__global__ __launch_bounds__(256, 2) void gemm8(
    const float* __restrict__ A, const float* __restrict__ W,
    const float* __restrict__ bias, const float2* __restrict__ stats,
    const float* __restrict__ lnsc, const float* __restrict__ lnbi,
    float* __restrict__ C)
{
  constexpr int BM = 128, BK = 16;
  constexpr int PA = BM + 4;
  constexpr int NJ = BN / 16;              // cols per thread: 8 or 4
  constexpr int S  = K / BK;
  constexpr int WPT = (BK * BN) / 1024;    // W float4 loads/thread: 2 or 1

  __shared__ float As[BK][PA];   // transposed: As[k][m]
  __shared__ float Ws[BK][BN];

  const int tid = threadIdx.x;
  const int tx  = tid & 15;
  const int ty  = tid >> 4;
  const int m0  = blockIdx.y * BM;
  const int n0  = blockIdx.x * BN;

  // A staging: 2 float4/thread, rows fixed for the whole K-loop
  const int ar0 = tid >> 2;            // 0..63
  const int ar1 = ar0 + 64;            // 64..127
  const int ac4 = (tid & 3) << 2;      // 0,4,8,12
  const float* Ap0 = A + (size_t)(m0 + ar0) * K + ac4;
  const float* Ap1 = A + (size_t)(m0 + ar1) * K + ac4;
  float2 st0, st1;
  if constexpr (LN) { st0 = stats[m0 + ar0]; st1 = stats[m0 + ar1]; }

  // W staging
  const int wr0 = tid / (BN / 4);
  const int wc0 = (tid % (BN / 4)) << 2;
  constexpr int WRS = 1024 / BN;       // k-row stride for 2nd W load (8 when BN=128)

  float4 aP0, aP1, wP0, wP1;

  // initial load (k0 = 0)
  aP0 = *(const float4*)(Ap0);
  aP1 = *(const float4*)(Ap1);
  if constexpr (LN) {
    float4 ls = *(const float4*)(lnsc + ac4);
    float4 lb = *(const float4*)(lnbi + ac4);
    aP0 = ln4(aP0, st0, ls, lb);
    aP1 = ln4(aP1, st1, ls, lb);
  }
  wP0 = *(const float4*)(W + (size_t)wr0 * N + n0 + wc0);
  if constexpr (WPT == 2)
    wP1 = *(const float4*)(W + (size_t)(wr0 + WRS) * N + n0 + wc0);

  float acc[8][NJ];
  #pragma unroll
  for (int i = 0; i < 8; ++i)
    #pragma unroll
    for (int j = 0; j < NJ; ++j) acc[i][j] = 0.f;

  for (int s = 0; s < S; ++s) {
    __syncthreads();
    As[ac4 + 0][ar0] = aP0.x;
    As[ac4 + 1][ar0] = aP0.y;
    As[ac4 + 2][ar0] = aP0.z;
    As[ac4 + 3][ar0] = aP0.w;
    As[ac4 + 0][ar1] = aP1.x;
    As[ac4 + 1][ar1] = aP1.y;
    As[ac4 + 2][ar1] = aP1.z;
    As[ac4 + 3][ar1] = aP1.w;
    *(float4*)&Ws[wr0][wc0] = wP0;
    if constexpr (WPT == 2) *(float4*)&Ws[wr0 + WRS][wc0] = wP1;
    __syncthreads();

    if (s + 1 < S) {
      const int k0 = (s + 1) * BK;
      aP0 = *(const float4*)(Ap0 + k0);
      aP1 = *(const float4*)(Ap1 + k0);
      if constexpr (LN) {
        float4 ls = *(const float4*)(lnsc + k0 + ac4);
        float4 lb = *(const float4*)(lnbi + k0 + ac4);
        aP0 = ln4(aP0, st0, ls, lb);
        aP1 = ln4(aP1, st1, ls, lb);
      }
      wP0 = *(const float4*)(W + (size_t)(k0 + wr0) * N + n0 + wc0);
      if constexpr (WPT == 2)
        wP1 = *(const float4*)(W + (size_t)(k0 + wr0 + WRS) * N + n0 + wc0);
    }

    #pragma unroll
    for (int kk = 0; kk < BK; ++kk) {
      float4 a0 = *(const float4*)&As[kk][ty * 8];
      float4 a1 = *(const float4*)&As[kk][ty * 8 + 4];
      float av[8] = {a0.x, a0.y, a0.z, a0.w, a1.x, a1.y, a1.z, a1.w};
      float wv[NJ];
      float4 w0 = *(const float4*)&Ws[kk][tx * NJ];
      wv[0] = w0.x; wv[1] = w0.y; wv[2] = w0.z; wv[3] = w0.w;
      if constexpr (NJ == 8) {
        float4 w1 = *(const float4*)&Ws[kk][tx * NJ + 4];
        wv[4] = w1.x; wv[5] = w1.y; wv[6] = w1.z; wv[7] = w1.w;
      }
      #pragma unroll
      for (int i = 0; i < 8; ++i)
        #pragma unroll
        for (int j = 0; j < NJ; ++j)
          acc[i][j] += av[i] * wv[j];
    }
  }

  // epilogue: + bias, coalesced float4 stores
  #pragma unroll
  for (int j4 = 0; j4 < NJ / 4; ++j4) {
    int col = n0 + tx * NJ + j4 * 4;
    float4 bb = *(const float4*)(bias + col);
    #pragma unroll
    for (int i = 0; i < 8; ++i) {
      int row = m0 + ty * 8 + i;
      float4 o;
      o.x = acc[i][j4 * 4 + 0] + bb.x;
      o.y = acc[i][j4 * 4 + 1] + bb.y;
      o.z = acc[i][j4 * 4 + 2] + bb.z;
      o.w = acc[i][j4 * 4 + 3] + bb.w;
      *(float4*)(C + (size_t)row * N + col) = o;
    }
  }
}

// ---- LIF scan (in-place) + deterministic per-(b,t) LN stats (mu, rs) ----
template<int H, int BPB>   // BPB batches per 256-thread block
__global__ __launch_bounds__(256) void lif_stats(
    float* __restrict__ cur, float2* __restrict__ stats)
{
  constexpr int T = 128;
  constexpr int WPB = H / 64;   // waves per batch
  const int tid  = threadIdx.x;
  const int h    = tid % H;
  const size_t b = (size_t)blockIdx.x * BPB + tid / H;
  float* p = cur + b * T * H + h;
  __shared__ float w1[4][T], w2[4][T];
  const int wv = tid >> 6, lane = tid & 63;
  float v = 0.f, ci = 0.f;
  for (int t0 = 0; t0 < T; t0 += 4) {
    float ic[4];
    #pragma unroll
    for (int u = 0; u < 4; ++u) ic[u] = p[(size_t)(t0 + u) * H];  // 4 in flight
    #pragma unroll
    for (int u = 0; u < 4; ++u) {
      ci = A_SYN * ci + ic[u];
      v  = A_MEM * v + OM_MEM * ci;
      bool sp = v >= 1.0f;
      float xx = 4.0f * (v - 1.0f);
      float e  = __expf(xx);
      float tp = 1.0f + e;
      float sg = 4.0f * e / (tp * tp);   // == BETA/(2(1+cosh(BETA(v-1))))
      float o  = (sp ? 2.0f : 0.0f) - sg;
      v = sp ? 0.0f : v;
      ic[u] = o;
      float s1 = o, s2 = o * o;
      #pragma unroll
      for (int off = 1; off < 64; off <<= 1) {
        s1 += __shfl_xor(s1, off);
        s2 += __shfl_xor(s2, off);
      }
      if (lane == 0) { w1[wv][t0 + u] = s1; w2[wv][t0 + u] = s2; }
    }
    #pragma unroll
    for (int u = 0; u < 4; ++u) p[(size_t)(t0 + u) * H] = ic[u];
  }
  __syncthreads();
  if (tid < T * BPB) {
    int t  = tid & (T - 1);
    int bs = tid >> 7;
    float s1 = 0.f, s2 = 0.f;
    #pragma unroll
    for (int w = 0; w < WPB; ++w) {
      s1 += w1[bs * WPB + w][t];
      s2 += w2[bs * WPB + w][t];
    }
    float mu  = s1 * (1.0f / H);
    float var = s2 * (1.0f / H) - mu * mu;
    float rs  = rsqrtf(var + 1e-6f);
    stats[((size_t)blockIdx.x * BPB + bs) * T + t] = make_float2(mu, rs);
  }
}

// ---- layer-2 LIF scan + mean pool (no x3 materialization) ----
__global__ __launch_bounds__(256) void lif_pool(
    const float* __restrict__ cur, float* __restrict__ pooled)
{
  constexpr int T = 128, H = 64;
  int flat = blockIdx.x * 256 + threadIdx.x;   // b*64 + h
  int b = flat >> 6, h = flat & 63;
  const float* p = cur + (size_t)b * T * H + h;
  float v = 0.f, ci = 0.f, sum = 0.f;
  for (int t0 = 0; t0 < T; t0 += 4) {
    float ic[4];
    #pragma unroll
    for (int u = 0; u < 4; ++u) ic[u] = p[(size_t)(t0 + u) * H];
    #pragma unroll
    for (int u = 0; u < 4; ++u) {
      ci = A_SYN * ci + ic[u];
      v  = A_MEM * v + OM_MEM * ci;
      bool sp = v >= 1.0f;
      float xx = 4.0f * (v - 1.0f);
      float e  = __expf(xx);
      float tp = 1.0f + e;
      float sg = 4.0f * e / (tp * tp);
      sum += (sp ? 2.0f : 0.0f) - sg;
      v = sp ? 0.0f : v;
    }
  }
  pooled[flat] = sum * (1.0f / 128.0f);
}

// ---- head: logits = pooled @ Wc + bc ; mean = mean(pooled) ----
__global__ __launch_bounds__(1024) void head_k(
    const float* __restrict__ pooled, const float* __restrict__ Wc,
    const float* __restrict__ bc, float* __restrict__ logits,
    float* __restrict__ meanp)
{
  const int tid = threadIdx.x;
  const int b = tid >> 1, c = tid & 1;
  float accl = 0.f;
  #pragma unroll 8
  for (int k = 0; k < 64; ++k) accl += pooled[b * 64 + k] * Wc[k * 2 + c];
  logits[tid] = accl + bc[c];

  float s = 0.f;
  for (int i2 = tid; i2 < 512 * 64; i2 += 1024) s += pooled[i2];
  #pragma unroll
  for (int off = 32; off; off >>= 1) s += __shfl_xor(s, off);
  __shared__ float red[16];
  const int wave = tid >> 6, lane = tid & 63;
  if (lane == 0) red[wave] = s;
  __syncthreads();
  if (tid == 0) {
    float tot = 0.f;
    #pragma unroll
    for (int w = 0; w < 16; ++w) tot += red[w];
    meanp[0] = tot * (1.0f / 32768.0f);
  }
}

extern "C" void kernel_launch(void* const* d_in, const int* in_sizes, int n_in,
                              void* d_out, int out_size, void* d_ws, size_t ws_size,
                              hipStream_t stream) {
  const float* x    = (const float*)d_in[0];   // [512,128,512]
  const float* W0   = (const float*)d_in[1];   // [512,256]
  const float* b0   = (const float*)d_in[2];
  const float* ln1s = (const float*)d_in[3];
  const float* ln1b = (const float*)d_in[4];
  const float* W1   = (const float*)d_in[5];   // [256,128]
  const float* b1   = (const float*)d_in[6];
  const float* ln2s = (const float*)d_in[7];
  const float* ln2b = (const float*)d_in[8];
  const float* W2   = (const float*)d_in[9];   // [128,64]
  const float* b2   = (const float*)d_in[10];
  const float* Wc   = (const float*)d_in[11];  // [64,2]
  const float* bc   = (const float*)d_in[12];

  float* out    = (float*)d_out;
  float* logits = out;                 // [512,2]
  float* pooled = out + 1024;          // [512,64]
  float* meanp  = out + 1024 + 32768;  // [1]

  char* ws = (char*)d_ws;
  float*  cur0   = (float*)ws;                               // 64 MB [65536,256]
  float*  cur1   = (float*)(ws + ((size_t)64 << 20));        // 32 MB [65536,128]
  float*  cur2   = (float*)(ws + ((size_t)96 << 20));        // 16 MB [65536,64]
  float2* stats0 = (float2*)(ws + ((size_t)112 << 20));                  // 512 KB
  float2* stats1 = (float2*)(ws + ((size_t)112 << 20) + (512 << 10));    // 512 KB

  // layer 0: GEMM [65536,512]x[512,256]; scan + stats for LN1
  gemm8<128, 512, 256, false><<<dim3(2, 512), 256, 0, stream>>>(
      x, W0, b0, nullptr, nullptr, nullptr, cur0);
  lif_stats<256, 1><<<512, 256, 0, stream>>>(cur0, stats0);
  // layer 1: LN1 fused into staging; scan + stats for LN2
  gemm8<128, 256, 128, true><<<dim3(1, 512), 256, 0, stream>>>(
      cur0, W1, b1, stats0, ln1s, ln1b, cur1);
  lif_stats<128, 2><<<256, 256, 0, stream>>>(cur1, stats1);
  // layer 2: LN2 fused; scan + pool (x3 never materialized)
  gemm8<64, 128, 64, true><<<dim3(1, 512), 256, 0, stream>>>(
      cur1, W2, b2, stats1, ln2s, ln2b, cur2);
  lif_pool<<<128, 256, 0, stream>>>(cur2, pooled);
  // head
  head_k<<<1, 1024, 0, stream>>>(pooled, Wc, bc, logits, meanp);
}